// Round 8
// baseline (412.741 us; speedup 1.0000x reference)
//
#include <hip/hip_runtime.h>
#include <math.h>

#define B_  4
#define S_  2048
#define D_  512
#define H_  8
#define FF_ 2048
#define W_  128
#define DH_ 64
#define TRD (3*D_)   // 1536
#define MR_ (B_*S_)  // 8192 rows
#define QKLD 1024    // q|k buffer row stride
#define SCQ 0.18033688011112042f   // 0.125 * log2(e)

typedef __attribute__((ext_vector_type(8)))  short short8;
typedef __attribute__((ext_vector_type(4)))  float f32x4;
typedef __attribute__((ext_vector_type(16))) float f32x16;

__device__ __forceinline__ short f2bf(float f) {
    unsigned u = __float_as_uint(f);
    unsigned r = (u + 0x7fff + ((u >> 16) & 1)) >> 16;   // RNE
    return (short)r;
}
__device__ __forceinline__ float bf2f(ushort u) {
    return __uint_as_float(((unsigned)u) << 16);
}
// pack two fp32 -> dword of two bf16 (truncation), low short = f0
__device__ __forceinline__ unsigned pack_bf_trunc(float f0, float f1) {
    return __builtin_amdgcn_perm(__float_as_uint(f1), __float_as_uint(f0), 0x07060302u);
}
__device__ __forceinline__ void gload_lds16(const ushort* g, short* l) {
    __builtin_amdgcn_global_load_lds(
        (const __attribute__((address_space(1))) void*)g,
        (__attribute__((address_space(3))) void*)l, 16, 0, 0);
}

// ---------------------------------------------------------------------------
// Fused fp32 -> bf16 conversion for src + 7 weight tensors.
// ---------------------------------------------------------------------------
struct CvtJobs { const float* s[8]; ushort* d[8]; int n[8]; };

__global__ __launch_bounds__(256) void cvt_kernel(CvtJobs jobs)
{
    int i4 = (blockIdx.x * 256 + threadIdx.x) * 4;
    #pragma unroll
    for (int j = 0; j < 8; j++) {
        if (i4 < jobs.n[j]) {
            float4 v = *(const float4*)(jobs.s[j] + i4);
            ushort4 o;
            o.x = (ushort)f2bf(v.x); o.y = (ushort)f2bf(v.y);
            o.z = (ushort)f2bf(v.z); o.w = (ushort)f2bf(v.w);
            *(ushort4*)(jobs.d[j] + i4) = o;
        }
    }
}

// ---------------------------------------------------------------------------
// bf16 MFMA GEMM, 128x128 tile (m97 recipe), BK=64, global_load_lds + XOR
// swizzle. Block 256 = 4 waves 2x2; wave = 64x64 = 4x4 16x16x32 tiles.
// vt mode (vt != nullptr): cols < 1024 -> C (ld 1024); cols >= 1024 are the
// V third -> written ONLY transposed into vt[bh][d][s'], s' = s bits2<->3
// swapped (the key permutation the attention PV path expects).
// ---------------------------------------------------------------------------
__global__ __launch_bounds__(256) void gemm_bf16_kernel(
    const ushort* __restrict__ A, int lda,
    const ushort* __restrict__ Wt,     // [N][K] row-major
    const float* __restrict__ bias,
    ushort* __restrict__ C, int ldc,
    ushort* __restrict__ vt,
    int K, int relu)
{
    __shared__ short As[128 * 64];
    __shared__ short Bs[128 * 64];
    const int tid  = threadIdx.x;
    const int w    = tid >> 6;
    const int lane = tid & 63;
    const int quad = lane >> 4;
    const int x    = lane & 15;
    const int wr = w >> 1, wc = w & 1;
    const int bm = blockIdx.y * 128;
    const int bn = blockIdx.x * 128;

    const int srow = w * 32 + (lane >> 3);
    const int scol = ((lane & 7) ^ (lane >> 3)) * 8;

    f32x4 acc[4][4];
    #pragma unroll
    for (int i = 0; i < 4; i++)
        #pragma unroll
        for (int j = 0; j < 4; j++) acc[i][j] = (f32x4)0.f;

    for (int k0 = 0; k0 < K; k0 += 64) {
        __syncthreads();
        #pragma unroll
        for (int c = 0; c < 4; c++) {
            const ushort* ga = A + (size_t)(bm + srow + c * 8) * lda + k0 + scol;
            gload_lds16(ga, &As[(w * 32 + c * 8) * 64]);
            const ushort* gb = Wt + (size_t)(bn + srow + c * 8) * K + k0 + scol;
            gload_lds16(gb, &Bs[(w * 32 + c * 8) * 64]);
        }
        __syncthreads();

        #pragma unroll
        for (int kc = 0; kc < 2; kc++) {
            short8 af[4], bf[4];
            int pcg = (kc * 4 + quad) ^ (x & 7);
            #pragma unroll
            for (int i = 0; i < 4; i++)
                af[i] = *(const short8*)&As[(wr * 64 + i * 16 + x) * 64 + pcg * 8];
            #pragma unroll
            for (int j = 0; j < 4; j++)
                bf[j] = *(const short8*)&Bs[(wc * 64 + j * 16 + x) * 64 + pcg * 8];
            #pragma unroll
            for (int i = 0; i < 4; i++)
                #pragma unroll
                for (int j = 0; j < 4; j++)
                    acc[i][j] = __builtin_amdgcn_mfma_f32_16x16x32_bf16(af[i], bf[j], acc[i][j], 0, 0, 0);
        }
    }

    if (vt) {
        #pragma unroll
        for (int i = 0; i < 4; i++) {
            int rowbase = bm + wr * 64 + i * 16 + quad * 4;   // row of r=0
            #pragma unroll
            for (int j = 0; j < 4; j++) {
                int col = bn + wc * 64 + j * 16 + x;
                float bv = bias ? bias[col] : 0.f;
                if (col < 1024) {
                    #pragma unroll
                    for (int r = 0; r < 4; r++)
                        C[(size_t)(rowbase + r) * QKLD + col] = (ushort)f2bf(acc[i][j][r] + bv);
                } else {
                    int cv = col - 1024, hh = cv >> 6, dd = cv & 63;
                    int bb = rowbase >> 11, ss = rowbase & 2047;
                    int quadp = ((quad & 1) << 1) | (quad >> 1);   // swap s bits 2<->3
                    int sp = (ss & ~15) | (quadp << 2);
                    ushort4 p4;
                    p4.x = (ushort)f2bf(acc[i][j][0] + bv);
                    p4.y = (ushort)f2bf(acc[i][j][1] + bv);
                    p4.z = (ushort)f2bf(acc[i][j][2] + bv);
                    p4.w = (ushort)f2bf(acc[i][j][3] + bv);
                    *(ushort4*)(vt + ((size_t)((bb * 8 + hh) * 64 + dd)) * S_ + sp) = p4;
                }
            }
        }
    } else {
        #pragma unroll
        for (int i = 0; i < 4; i++) {
            #pragma unroll
            for (int r = 0; r < 4; r++) {
                size_t row = (size_t)(bm + wr * 64 + i * 16 + quad * 4 + r);
                #pragma unroll
                for (int j = 0; j < 4; j++) {
                    int col = bn + wc * 64 + j * 16 + x;
                    float v = acc[i][j][r] + (bias ? bias[col] : 0.f);
                    if (relu) v = v > 0.f ? v : 0.f;
                    C[row * ldc + col] = (ushort)f2bf(v);
                }
            }
        }
    }
}

// ---------------------------------------------------------------------------
// Split-K (x2) bf16 GEMM, 128x128 tile -> fp32 partials. N=512 shapes.
// Grid (N/128, M/128, 2); partial z at P + z*MR_*D_.
// ---------------------------------------------------------------------------
__global__ __launch_bounds__(256) void gemm_bf16_splitk_kernel(
    const ushort* __restrict__ A, int lda,
    const ushort* __restrict__ Wt,
    float* __restrict__ P, int K)
{
    __shared__ short As[128 * 64];
    __shared__ short Bs[128 * 64];
    const int tid  = threadIdx.x;
    const int w    = tid >> 6;
    const int lane = tid & 63;
    const int quad = lane >> 4;
    const int x    = lane & 15;
    const int wr = w >> 1, wc = w & 1;
    const int bm = blockIdx.y * 128;
    const int bn = blockIdx.x * 128;
    const int kh = K >> 1;
    const int kbeg = blockIdx.z * kh;
    float* dst = P + (size_t)blockIdx.z * MR_ * D_;

    const int srow = w * 32 + (lane >> 3);
    const int scol = ((lane & 7) ^ (lane >> 3)) * 8;

    f32x4 acc[4][4];
    #pragma unroll
    for (int i = 0; i < 4; i++)
        #pragma unroll
        for (int j = 0; j < 4; j++) acc[i][j] = (f32x4)0.f;

    for (int k0 = kbeg; k0 < kbeg + kh; k0 += 64) {
        __syncthreads();
        #pragma unroll
        for (int c = 0; c < 4; c++) {
            const ushort* ga = A + (size_t)(bm + srow + c * 8) * lda + k0 + scol;
            gload_lds16(ga, &As[(w * 32 + c * 8) * 64]);
            const ushort* gb = Wt + (size_t)(bn + srow + c * 8) * K + k0 + scol;
            gload_lds16(gb, &Bs[(w * 32 + c * 8) * 64]);
        }
        __syncthreads();

        #pragma unroll
        for (int kc = 0; kc < 2; kc++) {
            short8 af[4], bf[4];
            int pcg = (kc * 4 + quad) ^ (x & 7);
            #pragma unroll
            for (int i = 0; i < 4; i++)
                af[i] = *(const short8*)&As[(wr * 64 + i * 16 + x) * 64 + pcg * 8];
            #pragma unroll
            for (int j = 0; j < 4; j++)
                bf[j] = *(const short8*)&Bs[(wc * 64 + j * 16 + x) * 64 + pcg * 8];
            #pragma unroll
            for (int i = 0; i < 4; i++)
                #pragma unroll
                for (int j = 0; j < 4; j++)
                    acc[i][j] = __builtin_amdgcn_mfma_f32_16x16x32_bf16(af[i], bf[j], acc[i][j], 0, 0, 0);
        }
    }

    #pragma unroll
    for (int i = 0; i < 4; i++)
        #pragma unroll
        for (int r = 0; r < 4; r++) {
            size_t row = (size_t)(bm + wr * 64 + i * 16 + quad * 4 + r);
            #pragma unroll
            for (int j = 0; j < 4; j++) {
                int col = bn + wc * 64 + j * 16 + x;
                dst[row * D_ + col] = acc[i][j][r];
            }
        }
}

// ---------------------------------------------------------------------------
// LayerNorm helpers / kernels.
// ---------------------------------------------------------------------------
__device__ __forceinline__ float wave_sum64(float v) {
    #pragma unroll
    for (int off = 32; off > 0; off >>= 1) v += __shfl_xor(v, off, 64);
    return v;
}
__device__ __forceinline__ void load8(const float* p, float* v) {
    *(float4*)&v[0] = *(const float4*)p;
    *(float4*)&v[4] = *(const float4*)(p + 4);
}
__device__ __forceinline__ void load8(const ushort* p, float* v) {
    short8 s = *(const short8*)p;
    #pragma unroll
    for (int i = 0; i < 8; i++) v[i] = bf2f((ushort)s[i]);
}
__device__ __forceinline__ void store8(float* p, const float* v) {
    *(float4*)p       = make_float4(v[0], v[1], v[2], v[3]);
    *(float4*)(p + 4) = make_float4(v[4], v[5], v[6], v[7]);
}
__device__ __forceinline__ void store8(ushort* p, const float* v) {
    short8 s;
    #pragma unroll
    for (int i = 0; i < 8; i++) s[i] = f2bf(v[i]);
    *(short8*)p = s;
}
__device__ __forceinline__ void ln_core(float* v, int lane,
    const float* g, const float* be, float* t) {
    float s = 0.f;
    #pragma unroll
    for (int i = 0; i < 8; i++) s += v[i];
    float mean = wave_sum64(s) * (1.0f / 512.0f);
    float vs = 0.f;
    #pragma unroll
    for (int i = 0; i < 8; i++) { float d = v[i] - mean; vs += d * d; }
    float var = wave_sum64(vs) * (1.0f / 512.0f);
    float r = rsqrtf(var + 1e-5f);
    const int c = lane * 8;
    #pragma unroll
    for (int i = 0; i < 8; i++) t[i] = (v[i] - mean) * r * g[c + i] + be[c + i];
}

template <typename TA, typename TO>
__global__ __launch_bounds__(256) void addln_kernel(
    const TA* __restrict__ a,
    const float* __restrict__ g, const float* __restrict__ be,
    TO* __restrict__ out)
{
    const int lane = threadIdx.x & 63;
    const int row  = blockIdx.x * 4 + (threadIdx.x >> 6);
    const size_t base = (size_t)row * D_ + lane * 8;
    float v[8], t[8];
    load8(a + base, v);
    ln_core(v, lane, g, be, t);
    store8(out + base, t);
}

// out = LN(a + p0 + p1 + bias)  -- split-K combine fused into Add+LN
template <typename TA, typename TO>
__global__ __launch_bounds__(256) void ln_split_kernel(
    const TA* __restrict__ a,
    const float* __restrict__ p0, const float* __restrict__ p1,
    const float* __restrict__ bias,
    const float* __restrict__ g, const float* __restrict__ be,
    TO* __restrict__ out)
{
    const int lane = threadIdx.x & 63;
    const int row  = blockIdx.x * 4 + (threadIdx.x >> 6);
    const size_t base = (size_t)row * D_ + lane * 8;
    float v[8], w0[8], w1[8], t[8];
    load8(a + base, v);
    load8(p0 + base, w0);
    load8(p1 + base, w1);
    const int c = lane * 8;
    #pragma unroll
    for (int i = 0; i < 8; i++) v[i] += w0[i] + w1[i] + bias[c + i];
    ln_core(v, lane, g, be, t);
    store8(out + base, t);
}

// ---------------------------------------------------------------------------
// Generic bf16 512x512 transpose (weight prep). Grid (8,8).
// ---------------------------------------------------------------------------
__global__ __launch_bounds__(256) void transpose512_kernel(
    const ushort* __restrict__ in, ushort* __restrict__ out)
{
    __shared__ ushort T[64][72];
    const int t  = threadIdx.x;
    const int r0 = blockIdx.y * 64, c0 = blockIdx.x * 64;
    {
        int row = t >> 2, col = (t & 3) * 16;
        const ushort* s = in + (size_t)(r0 + row) * 512 + c0 + col;
        *(short8*)&T[row][col]     = *(const short8*)s;
        *(short8*)&T[row][col + 8] = *(const short8*)(s + 8);
    }
    __syncthreads();
    {
        int d = t >> 2, sc = (t & 3) * 16;
        ushort tmp[16];
        #pragma unroll
        for (int k = 0; k < 16; k++) tmp[k] = T[sc + k][d];
        ushort* dptr = out + (size_t)(c0 + d) * 512 + r0 + sc;
        *(short8*)dptr       = *(const short8*)&tmp[0];
        *(short8*)(dptr + 8) = *(const short8*)&tmp[8];
    }
}

// ---------------------------------------------------------------------------
// bfuse[n] = sum_m gl_w[n][m] * out_proj_b[m] + gl_b[n]  (fp32). Wave/row.
// ---------------------------------------------------------------------------
__global__ __launch_bounds__(256) void fuse_bias_kernel(
    const float* __restrict__ gl_w, const float* __restrict__ opb,
    const float* __restrict__ gl_b, float* __restrict__ bf)
{
    const int lane = threadIdx.x & 63;
    const int row  = blockIdx.x * 4 + (threadIdx.x >> 6);
    float s = 0.f;
    #pragma unroll
    for (int i = 0; i < 8; i++) {
        int m = lane * 8 + i;
        s += gl_w[(size_t)row * 1024 + m] * opb[m];
    }
    s = wave_sum64(s);
    if (lane == 0) bf[row] = s + gl_b[row];
}

// ---------------------------------------------------------------------------
// Vectorized RoPE (+SCQ scale on q) in place on q|k buffer (ld 1024).
// ---------------------------------------------------------------------------
__global__ __launch_bounds__(256) void rope_kernel(ushort* __restrict__ qk)
{
    int idx = blockIdx.x * 256 + threadIdx.x;   // < B*S*H*4
    int d8 = idx & 3;
    int h  = (idx >> 2) & 7;
    int bs = idx >> 5;
    int pos = bs & (S_ - 1);
    ushort* base = qk + (size_t)bs * QKLD + h * 64 + d8 * 8;
    float q1[8], q2[8], k1[8], k2[8];
    load8(base, q1);       load8(base + 32, q2);
    load8(base + 512, k1); load8(base + 544, k2);
    float oq1[8], oq2[8], ok1[8], ok2[8];
    #pragma unroll
    for (int i = 0; i < 8; i++) {
        int d = d8 * 8 + i;
        float inv_freq = exp2f(-(float)d * (2.0f / 64.0f) * 13.287712379549449f);
        float ang = (float)pos * inv_freq;
        float sn, cs;
        __sincosf(ang, &sn, &cs);
        oq1[i] = (q1[i] * cs - q2[i] * sn) * SCQ;
        oq2[i] = (q2[i] * cs + q1[i] * sn) * SCQ;
        ok1[i] = k1[i] * cs - k2[i] * sn;
        ok2[i] = k2[i] * cs + k1[i] * sn;
    }
    store8(base, oq1);       store8(base + 32, oq2);
    store8(base + 512, ok1); store8(base + 544, ok2);
}

// ---------------------------------------------------------------------------
// Merged attention (global z=0 / local z=1). 32x32x16 MFMA, S^T layout,
// no-max exp2 softmax, register-resident P (bit-swapped V^T key order makes
// PV B-fragments consecutive S^T regs), in-block split-K over 2 wave-pairs.
// Global path: specialized loop, hoisted staging pointers (no per-tile
// 64-bit address rebuild), no mask. Local path: 2-iteration masked loop.
// ---------------------------------------------------------------------------
__global__ __launch_bounds__(256) void attn_kernel(
    const ushort* __restrict__ qkG, const ushort* __restrict__ vtG,
    const ushort* __restrict__ qkL, const ushort* __restrict__ vtL,
    ushort* __restrict__ cat)
{
    __shared__ short KsS[2][64 * 64];
    __shared__ short VtS[2][64 * 64];
    __shared__ float Lw[4][32];

    const int LOCAL = blockIdx.z;
    const ushort* qk = LOCAL ? qkL : qkG;
    const ushort* vt = LOCAL ? vtL : vtG;
    ushort* outp = cat + (LOCAL ? D_ : 0);

    const int tid  = threadIdx.x;
    const int w    = tid >> 6;
    const int lane = tid & 63;
    const int hl   = lane >> 5;
    const int c    = lane & 31;
    const int ks   = w >> 1;
    const int qh   = w & 1;
    const int bh = blockIdx.y;
    const int b = bh >> 3, h = bh & 7;
    const int qbase = blockIdx.x * 64;
    const int q0 = qbase + qh * 32;
    const size_t bS = (size_t)b * S_;
    const size_t vbase = (size_t)bh * DH_;

    // Q fragments (B-operand layout); global folds SCQ, local pre-scaled
    short8 aq[4];
    {
        const ushort* qp = qk + (bS + q0 + c) * QKLD + h * 64;
        #pragma unroll
        for (int kc = 0; kc < 4; kc++) {
            short8 raw = *(const short8*)(qp + kc * 16 + hl * 8);
            if (LOCAL) aq[kc] = raw;
            else {
                #pragma unroll
                for (int j = 0; j < 8; j++) aq[kc][j] = f2bf(bf2f((ushort)raw[j]) * SCQ);
            }
        }
    }

    f32x16 ot[2];
    ot[0] = (f32x16)0.f; ot[1] = (f32x16)0.f;
    float lpa = 0.f, lpb = 0.f;   // packed-add pair

    // staging geometry (shared by both paths)
    const int rowk = qh * 32 + (lane >> 3);         // row within 64-tile
    const int cg   = (lane & 7) ^ (lane >> 3);      // swizzled colgroup
    short* ldsk = &KsS[ks][(qh * 32) * 64];
    short* ldsv = &VtS[ks][(qh * 32) * 64];

    if (!LOCAL) {
        // hoisted global pointers: pair ks covers keys [ks*1024, +1024)
        const ushort* gk = qk + (bS + ks * 1024 + rowk) * QKLD + 512 + h * 64 + cg * 8;
        const ushort* gv = vt + (vbase + rowk) * S_ + ks * 1024 + cg * 8;
        for (int it = 0; it < 16; it++) {
            __syncthreads();
            #pragma unroll
            for (int cc = 0; cc < 4; cc++) {
                gload_lds16(gk + (size_t)(cc * 8) * QKLD, ldsk + cc * 8 * 64);
                gload_lds16(gv + (size_t)(cc * 8) * S_,   ldsv + cc * 8 * 64);
            }
            __syncthreads();
            gk += 64 * QKLD;
            gv += 64;

            // S^T = K Q^T
            f32x16 e0 = (f32x16)0.f, e1 = (f32x16)0.f;
            #pragma unroll
            for (int kc = 0; kc < 4; kc++) {
                int pcg = (kc * 2 + hl) ^ (c & 7);
                short8 ak0 = *(const short8*)&KsS[ks][c * 64 + pcg * 8];
                e0 = __builtin_amdgcn_mfma_f32_32x32x16_bf16(ak0, aq[kc], e0, 0, 0, 0);
                short8 ak1 = *(const short8*)&KsS[ks][(32 + c) * 64 + pcg * 8];
                e1 = __builtin_amdgcn_mfma_f32_32x32x16_bf16(ak1, aq[kc], e1, 0, 0, 0);
            }
            // exp2 (no max, no mask) + l partials
            #pragma unroll
            for (int r = 0; r < 16; r++) { e0[r] = exp2f(e0[r]); }
            #pragma unroll
            for (int r = 0; r < 16; r++) { e1[r] = exp2f(e1[r]); }
            #pragma unroll
            for (int r = 0; r < 8; r++) {
                lpa += e0[2 * r] + e1[2 * r];
                lpb += e0[2 * r + 1] + e1[2 * r + 1];
            }
            // O^T += V^T P^T (register P)
            #pragma unroll
            for (int t = 0; t < 4; t++) {
                const f32x16& e = (t < 2) ? e0 : e1;
                const int rb = 8 * (t & 1);
                uint4 u;
                u.x = pack_bf_trunc(e[rb + 0], e[rb + 1]);
                u.y = pack_bf_trunc(e[rb + 2], e[rb + 3]);
                u.z = pack_bf_trunc(e[rb + 4], e[rb + 5]);
                u.w = pack_bf_trunc(e[rb + 6], e[rb + 7]);
                short8 bp = *(short8*)&u;
                #pragma unroll
                for (int dt = 0; dt < 2; dt++) {
                    int row = dt * 32 + c;
                    int pcg = (t * 2 + hl) ^ (c & 7);
                    short8 av = *(const short8*)&VtS[ks][row * 64 + pcg * 8];
                    ot[dt] = __builtin_amdgcn_mfma_f32_32x32x16_bf16(av, bp, ot[dt], 0, 0, 0);
                }
            }
        }
    } else {
        for (int it = 0; it < 2; it++) {
            const int tile  = ks * 2 + it;
            const int kbase = (qbase >> 7) * 128 - 128 + tile * 64;
            const bool active = (kbase >= 0 && kbase <= qbase + 63);
            __syncthreads();
            if (active) {
                #pragma unroll
                for (int cc = 0; cc < 4; cc++) {
                    gload_lds16(qk + (bS + kbase + rowk + cc * 8) * QKLD + 512 + h * 64 + cg * 8,
                                ldsk + cc * 8 * 64);
                    gload_lds16(vt + (vbase + rowk + cc * 8) * S_ + kbase + cg * 8,
                                ldsv + cc * 8 * 64);
                }
            }
            __syncthreads();
            if (!active) continue;
            const bool diag = (kbase == qbase);

            f32x16 e0 = (f32x16)0.f, e1 = (f32x16)0.f;
            #pragma unroll
            for (int kc = 0; kc < 4; kc++) {
                int pcg = (kc * 2 + hl) ^ (c & 7);
                short8 ak0 = *(const short8*)&KsS[ks][c * 64 + pcg * 8];
                e0 = __builtin_amdgcn_mfma_f32_32x32x16_bf16(ak0, aq[kc], e0, 0, 0, 0);
                short8 ak1 = *(const short8*)&KsS[ks][(32 + c) * 64 + pcg * 8];
                e1 = __builtin_amdgcn_mfma_f32_32x32x16_bf16(ak1, aq[kc], e1, 0, 0, 0);
            }
            const int qi = q0 + c;
            #pragma unroll
            for (int mt = 0; mt < 2; mt++) {
                f32x16& e = mt ? e1 : e0;
                #pragma unroll
                for (int r = 0; r < 16; r++) {
                    float p = exp2f(e[r]);
                    if (diag) {
                        int key = kbase + mt * 32 + (r & 3) + 8 * (r >> 2) + 4 * hl;
                        if (key > qi) p = 0.f;
                    }
                    e[r] = p;
                }
            }
            #pragma unroll
            for (int r = 0; r < 8; r++) {
                lpa += e0[2 * r] + e1[2 * r];
                lpb += e0[2 * r + 1] + e1[2 * r + 1];
            }
            #pragma unroll
            for (int t = 0; t < 4; t++) {
                const f32x16& e = (t < 2) ? e0 : e1;
                const int rb = 8 * (t & 1);
                uint4 u;
                u.x = pack_bf_trunc(e[rb + 0], e[rb + 1]);
                u.y = pack_bf_trunc(e[rb + 2], e[rb + 3]);
                u.z = pack_bf_trunc(e[rb + 4], e[rb + 5]);
                u.w = pack_bf_trunc(e[rb + 6], e[rb + 7]);
                short8 bp = *(short8*)&u;
                #pragma unroll
                for (int dt = 0; dt < 2; dt++) {
                    int row = dt * 32 + c;
                    int pcg = (t * 2 + hl) ^ (c & 7);
                    short8 av = *(const short8*)&VtS[ks][row * 64 + pcg * 8];
                    ot[dt] = __builtin_amdgcn_mfma_f32_32x32x16_bf16(av, bp, ot[dt], 0, 0, 0);
                }
            }
        }
    }

    // l for q=c over my key-chunk
    float lp = lpa + lpb;
    lp += __shfl_xor(lp, 32, 64);
    if (hl == 0) Lw[w][c] = lp;
    __syncthreads();   // tile reads done; staging bufs free; Lw visible

    // cross-pair combine: waves 2,3 dump O^T partials into dead KsS region
    float* scr = (float*)&KsS[0][0];
    if (w >= 2) {
        float* dst = scr + (w - 2) * 2048;
        #pragma unroll
        for (int dt = 0; dt < 2; dt++)
            #pragma unroll
            for (int r = 0; r < 16; r++)
                dst[(dt * 16 + r) * 64 + lane] = ot[dt][r];
    }
    __syncthreads();
    if (w < 2) {
        const float* srcp = scr + w * 2048;
        #pragma unroll
        for (int dt = 0; dt < 2; dt++)
            #pragma unroll
            for (int r = 0; r < 16; r++)
                ot[dt][r] += srcp[(dt * 16 + r) * 64 + lane];
        float inv = 1.0f / (Lw[w][c] + Lw[w + 2][c]);

        short* tr = (short*)&VtS[0][0] + w * 2304;
        #pragma unroll
        for (int dt = 0; dt < 2; dt++)
            #pragma unroll
            for (int rq = 0; rq < 4; rq++) {
                uint2 pkv;
                pkv.x = pack_bf_trunc(ot[dt][rq * 4 + 0] * inv, ot[dt][rq * 4 + 1] * inv);
                pkv.y = pack_bf_trunc(ot[dt][rq * 4 + 2] * inv, ot[dt][rq * 4 + 3] * inv);
                *(uint2*)&tr[c * 72 + dt * 32 + 8 * rq + 4 * hl] = pkv;
            }
        asm volatile("s_waitcnt lgkmcnt(0)" ::: "memory");
        __builtin_amdgcn_wave_barrier();
        {
            int q  = lane >> 1;
            int d0 = (lane & 1) * 32;
            short8 v0 = *(const short8*)&tr[q * 72 + d0];
            short8 v1 = *(const short8*)&tr[q * 72 + d0 + 8];
            short8 v2 = *(const short8*)&tr[q * 72 + d0 + 16];
            short8 v3 = *(const short8*)&tr[q * 72 + d0 + 24];
            ushort* op = outp + (bS + q0 + q) * 1024 + h * 64 + d0;
            *(short8*)(op)      = v0;
            *(short8*)(op + 8)  = v1;
            *(short8*)(op + 16) = v2;
            *(short8*)(op + 24) = v3;
        }
    }
}

// ---------------------------------------------------------------------------
extern "C" void kernel_launch(void* const* d_in, const int* in_sizes, int n_in,
                              void* d_out, int out_size, void* d_ws, size_t ws_size,
                              hipStream_t stream)
{
    (void)in_sizes; (void)n_in; (void)out_size; (void)ws_size;
    const float* src        = (const float*)d_in[0];
    const float* in_proj_w  = (const float*)d_in[1];
    const float* in_proj_b  = (const float*)d_in[2];
    const float* out_proj_w = (const float*)d_in[3];
    const float* out_proj_b = (const float*)d_in[4];
    const float* ln_g       = (const float*)d_in[5];
    const float* ln_b       = (const float*)d_in[6];
    const float* qkv_w      = (const float*)d_in[7];
    const float* to_out_w   = (const float*)d_in[8];
    const float* gl_w       = (const float*)d_in[9];
    const float* gl_b       = (const float*)d_in[10];
    const float* norm1_g    = (const float*)d_in[11];
    const float* norm1_b    = (const float*)d_in[12];
    const float* lin1_w     = (const float*)d_in[13];
    const float* lin1_b     = (const float*)d_in[14];
    const float* lin2_w     = (const float*)d_in[15];
    const float* lin2_b     = (const float*)d_in[16];
    const float* norm2_g    = (const float*)d_in[17];
    const float* norm2_b    = (const float*)d_in[18];
    float* out = (float*)d_out;

    // --- workspace (ushort units) ---
    ushort* ws16   = (ushort*)d_ws;
    ushort* src_bf = ws16;
    ushort* wi_bf  = src_bf + (size_t)MR_ * D_;
    ushort* wq_bf  = wi_bf  + TRD * D_;
    ushort* wo_bf  = wq_bf  + TRD * D_;
    ushort* wt_bf  = wo_bf  + D_ * D_;
    ushort* wg_bf  = wt_bf  + D_ * D_;
    ushort* w1_bf  = wg_bf  + D_ * 2 * D_;
    ushort* w2_bf  = w1_bf  + FF_ * D_;
    ushort* opwT   = w2_bf  + D_ * FF_;
    ushort* towT   = opwT   + D_ * D_;
    ushort* wcat   = towT   + D_ * D_;              // 512*1024
    float*  bfuse  = (float*)(wcat + D_ * 2 * D_);  // 512 fp32
    ushort* buf1   = (ushort*)(bfuse + D_);         // 8192*512 (x)
    ushort* h1b    = buf1 + (size_t)MR_ * D_;       // 8192*512
    ushort* qkG    = h1b  + (size_t)MR_ * D_;       // 8192*1024
    ushort* vtg    = qkG  + (size_t)MR_ * QKLD;     // 8192*512
    ushort* qkL    = vtg  + (size_t)MR_ * D_;       // 8192*1024
    ushort* vtl    = qkL  + (size_t)MR_ * QKLD;     // 8192*512
    ushort* cat    = vtl  + (size_t)MR_ * D_;       // 8192*1024
    // overlays (dead by reuse time):
    float*  part   = (float*)qkG;                   // 2 x 8192*512 fp32
    ushort* ff1    = qkL + (size_t)MR_ * D_;        // 8192*2048

    dim3 blk256(256);

    // 0. fp32 -> bf16 conversions
    CvtJobs jobs;
    jobs.s[0] = src;        jobs.d[0] = src_bf; jobs.n[0] = MR_ * D_;
    jobs.s[1] = in_proj_w;  jobs.d[1] = wi_bf;  jobs.n[1] = TRD * D_;
    jobs.s[2] = qkv_w;      jobs.d[2] = wq_bf;  jobs.n[2] = TRD * D_;
    jobs.s[3] = out_proj_w; jobs.d[3] = wo_bf;  jobs.n[3] = D_ * D_;
    jobs.s[4] = to_out_w;   jobs.d[4] = wt_bf;  jobs.n[4] = D_ * D_;
    jobs.s[5] = gl_w;       jobs.d[5] = wg_bf;  jobs.n[5] = D_ * 2 * D_;
    jobs.s[6] = lin1_w;     jobs.d[6] = w1_bf;  jobs.n[6] = FF_ * D_;
    jobs.s[7] = lin2_w;     jobs.d[7] = w2_bf;  jobs.n[7] = D_ * FF_;
    cvt_kernel<<<dim3(4096), blk256, 0, stream>>>(jobs);

    // 0b. weight prep: wcat = [G1@OPW | G2@TOW], bias fold
    transpose512_kernel<<<dim3(8, 8), blk256, 0, stream>>>(wo_bf, opwT);
    transpose512_kernel<<<dim3(8, 8), blk256, 0, stream>>>(wt_bf, towT);
    gemm_bf16_kernel<<<dim3(4, 4), blk256, 0, stream>>>(
        wg_bf, 2 * D_, opwT, nullptr, wcat, 2 * D_, nullptr, D_, 0);
    gemm_bf16_kernel<<<dim3(4, 4), blk256, 0, stream>>>(
        wg_bf + D_, 2 * D_, towT, nullptr, wcat + D_, 2 * D_, nullptr, D_, 0);
    fuse_bias_kernel<<<dim3(D_ / 4), blk256, 0, stream>>>(gl_w, out_proj_b, gl_b, bfuse);

    // 1. global qkv = src @ in_proj^T + b  -> qkG (q|k) + vtg (V^T, permuted)
    gemm_bf16_kernel<<<dim3(TRD / 128, MR_ / 128), blk256, 0, stream>>>(
        src_bf, D_, wi_bf, in_proj_b, qkG, QKLD, vtg, D_, 0);
    // 2. x = LN(src) -> buf1
    addln_kernel<float, ushort><<<dim3(MR_ / 4), blk256, 0, stream>>>(
        src, ln_g, ln_b, buf1);
    // 3. local qkv = x @ qkv_w^T -> qkL + vtl
    gemm_bf16_kernel<<<dim3(TRD / 128, MR_ / 128), blk256, 0, stream>>>(
        buf1, D_, wq_bf, nullptr, qkL, QKLD, vtl, D_, 0);
    // 4. RoPE (+SCQ on q) on qkL
    rope_kernel<<<dim3((B_ * S_ * H_ * 4) / 256), blk256, 0, stream>>>(qkL);
    // 5. merged attention -> cat [go_pre | lo_pre]
    attn_kernel<<<dim3(S_ / 64, B_ * H_, 2), blk256, 0, stream>>>(
        qkG, vtg, qkL, vtl, cat);
    // 6. src2 partials = cat @ wcat^T (split-K x2, K=1024)
    gemm_bf16_splitk_kernel<<<dim3(D_ / 128, MR_ / 128, 2), blk256, 0, stream>>>(
        cat, 2 * D_, wcat, part, 2 * D_);
    // 7. h1 = LN(src + p0 + p1 + bfuse) -> h1b
    ln_split_kernel<float, ushort><<<dim3(MR_ / 4), blk256, 0, stream>>>(
        src, part, part + (size_t)MR_ * D_, bfuse, norm1_g, norm1_b, h1b);
    // 8. ff1 = relu(h1 @ lin1^T + b)
    gemm_bf16_kernel<<<dim3(FF_ / 128, MR_ / 128), blk256, 0, stream>>>(
        h1b, D_, w1_bf, lin1_b, ff1, FF_, nullptr, D_, 1);
    // 9. ff2 partials = ff1 @ lin2^T (split-K x2, K=2048)
    gemm_bf16_splitk_kernel<<<dim3(D_ / 128, MR_ / 128, 2), blk256, 0, stream>>>(
        ff1, FF_, w2_bf, part, FF_);
    // 10. out = LN(h1 + p0 + p1 + lin2_b) -> d_out (fp32)
    ln_split_kernel<ushort, float><<<dim3(MR_ / 4), blk256, 0, stream>>>(
        h1b, part, part + (size_t)MR_ * D_, lin2_b, norm2_g, norm2_b, out);
}